// Round 1
// baseline (103.209 us; speedup 1.0000x reference)
//
#include <hip/hip_runtime.h>

// LinearAttention fused pipeline, MI355X gfx950.
// x[16,256,64,64] f32 -> transpose-convert xh[b][n][c] fp16
// GEMM-Q:  qh[b][n][c]  = elu1(xh . WqT)          (fp16, 32MiB)
// GEMM-KV: kv[b][c], den[b][c] reduced in-register (fp32 atomics)
// ws[b][o][c] = w_out[o][c] * kv/den * 1024        (fp16)
// GEMM2+LN fused -> d_out f32 [b][c][n]

#define NB 16
#define NC 256
#define NN 4096
#define LN_EPS 1e-5f
#define IOSCALE (1.0f/1024.0f)

typedef _Float16 f16;
typedef _Float16 f16x8 __attribute__((ext_vector_type(8)));
typedef _Float16 f16x4v __attribute__((ext_vector_type(4)));
typedef float f32x4 __attribute__((ext_vector_type(4)));

typedef __attribute__((address_space(1))) const unsigned int* as1cu32;
typedef __attribute__((address_space(3))) unsigned int* as3u32;

__device__ __forceinline__ void gload16(const void* g, void* l) {
  __builtin_amdgcn_global_load_lds((as1cu32)g, (as3u32)l, 16, 0, 0);
}

__device__ __forceinline__ float elu1(float x) {
  return x > 0.f ? x + 1.f : __expf(x);
}

__global__ __launch_bounds__(256) void k_convw(const float* __restrict__ w,
                                               f16* __restrict__ wh, int n) {
  int i = blockIdx.x * 256 + threadIdx.x;
  if (i < n) wh[i] = (f16)w[i];
}

// x[b][c][n] f32 -> xh[b][n][c] f16. 64x64 tiles via LDS.
__global__ __launch_bounds__(256) void k_transpose(const float* __restrict__ x,
                                                   f16* __restrict__ xh) {
  __shared__ float t[64 * 65];
  const int b = blockIdx.z, c0 = blockIdx.y * 64, n0 = blockIdx.x * 64;
  const int tid = threadIdx.x;
#pragma unroll
  for (int i = 0; i < 4; ++i) {
    int lin = tid + i * 256;     // 0..1023
    int r = lin >> 4;            // c row 0..63
    int cg = lin & 15;           // 16 col-groups of 4
    const float4 v = *reinterpret_cast<const float4*>(
        &x[((size_t)(b * NC + c0 + r)) * NN + n0 + cg * 4]);
    t[r * 65 + cg * 4 + 0] = v.x;
    t[r * 65 + cg * 4 + 1] = v.y;
    t[r * 65 + cg * 4 + 2] = v.z;
    t[r * 65 + cg * 4 + 3] = v.w;
  }
  __syncthreads();
#pragma unroll
  for (int i = 0; i < 4; ++i) {
    int lin = tid + i * 256;
    int nr = lin >> 4;           // n row 0..63
    int cg = lin & 15;
    f16x4v h;
    h[0] = (f16)t[(cg * 4 + 0) * 65 + nr];
    h[1] = (f16)t[(cg * 4 + 1) * 65 + nr];
    h[2] = (f16)t[(cg * 4 + 2) * 65 + nr];
    h[3] = (f16)t[(cg * 4 + 3) * 65 + nr];
    *reinterpret_cast<f16x4v*>(&xh[((size_t)(b * NN + n0 + nr)) * NC + c0 + cg * 4]) = h;
  }
}

// D[n][o] = sum_c xh[n][c] * wh[o][c], o in [0,256) (q rows). elu+1, store qh[b][n][o].
__global__ __launch_bounds__(256) void k_gemm_q(const f16* __restrict__ xh,
                                                const f16* __restrict__ wh,
                                                f16* __restrict__ qh) {
  __shared__ __align__(16) f16 At[128 * 64];
  __shared__ __align__(16) f16 Bt[128 * 64];
  const int b = blockIdx.z;
  const int n0 = blockIdx.x * 128;
  const int o0 = blockIdx.y * 128;
  const int tid = threadIdx.x;
  const int lane = tid & 63;
  const int wv = tid >> 6;
  const int wn = wv >> 1, wo = wv & 1;
  const int l15 = lane & 15, lg = lane >> 4;
  const int srow = lane >> 3;
  const int sch = (lane & 7) * 8;

  f32x4 acc[4][4] = {};

  for (int ks = 0; ks < 4; ++ks) {
    const int c0 = ks * 64;
#pragma unroll
    for (int it = 0; it < 4; ++it) {
      const int seg = wv * 4 + it;
      const int row = seg * 8 + srow;
      gload16(xh + ((size_t)(b * NN + n0 + row)) * NC + c0 + sch, At + seg * 512);
      gload16(wh + (size_t)(o0 + row) * NC + c0 + sch, Bt + seg * 512);
    }
    __syncthreads();
#pragma unroll
    for (int kk = 0; kk < 2; ++kk) {
      const int kb = kk * 32 + lg * 8;
      f16x8 af[4], bf[4];
#pragma unroll
      for (int m = 0; m < 4; ++m)
        af[m] = *(const f16x8*)(At + (wn * 64 + m * 16 + l15) * 64 + kb);
#pragma unroll
      for (int n = 0; n < 4; ++n)
        bf[n] = *(const f16x8*)(Bt + (wo * 64 + n * 16 + l15) * 64 + kb);
#pragma unroll
      for (int m = 0; m < 4; ++m)
#pragma unroll
        for (int n = 0; n < 4; ++n)
          acc[m][n] = __builtin_amdgcn_mfma_f32_16x16x32_f16(af[m], bf[n], acc[m][n], 0, 0, 0);
    }
    __syncthreads();
  }
#pragma unroll
  for (int m = 0; m < 4; ++m) {
    const int nr = n0 + wn * 64 + m * 16 + lg * 4;
#pragma unroll
    for (int n = 0; n < 4; ++n) {
      const int oc = o0 + wo * 64 + n * 16 + l15;
#pragma unroll
      for (int j = 0; j < 4; ++j)
        qh[((size_t)(b * NN + nr + j)) * NC + oc] = (f16)elu1(acc[m][n][j]);
    }
  }
}

// k' = elu1(xh.WkT), v = xh.WvT computed per tile; reduce kv += k'*v, den += k' over n.
// Block tile: 128 n x 128 cols, cols 0..63 = k channels cc0.., cols 64..127 = v same channels.
__global__ __launch_bounds__(256) void k_gemm_kv(const f16* __restrict__ xh,
                                                 const f16* __restrict__ wh,
                                                 float* __restrict__ kv,
                                                 float* __restrict__ den) {
  __shared__ __align__(16) f16 At[128 * 64];
  __shared__ __align__(16) f16 Bt[128 * 64];
  const int b = blockIdx.z;
  const int n0 = blockIdx.x * 128;
  const int cc0 = blockIdx.y * 64;
  const int tid = threadIdx.x;
  const int lane = tid & 63;
  const int wv = tid >> 6;   // wave covers n rows [wv*32, wv*32+32)
  const int l15 = lane & 15, lg = lane >> 4;
  const int srow = lane >> 3;
  const int sch = (lane & 7) * 8;

  f32x4 acc[2][8] = {};

  for (int ks = 0; ks < 4; ++ks) {
    const int c0 = ks * 64;
#pragma unroll
    for (int it = 0; it < 4; ++it) {
      const int seg = wv * 4 + it;
      const int row = seg * 8 + srow;
      gload16(xh + ((size_t)(b * NN + n0 + row)) * NC + c0 + sch, At + seg * 512);
      const int wrow = row < 64 ? 256 + cc0 + row : 512 + cc0 + (row - 64);
      gload16(wh + (size_t)wrow * NC + c0 + sch, Bt + seg * 512);
    }
    __syncthreads();
#pragma unroll
    for (int kk = 0; kk < 2; ++kk) {
      const int kb = kk * 32 + lg * 8;
      f16x8 af[2], bf[8];
#pragma unroll
      for (int m = 0; m < 2; ++m)
        af[m] = *(const f16x8*)(At + (wv * 32 + m * 16 + l15) * 64 + kb);
#pragma unroll
      for (int f = 0; f < 8; ++f)
        bf[f] = *(const f16x8*)(Bt + (f * 16 + l15) * 64 + kb);
#pragma unroll
      for (int m = 0; m < 2; ++m)
#pragma unroll
        for (int f = 0; f < 8; ++f)
          acc[m][f] = __builtin_amdgcn_mfma_f32_16x16x32_f16(af[m], bf[f], acc[m][f], 0, 0, 0);
    }
    __syncthreads();
  }
  float pkv[4], pden[4];
#pragma unroll
  for (int f = 0; f < 4; ++f) { pkv[f] = 0.f; pden[f] = 0.f; }
#pragma unroll
  for (int f = 0; f < 4; ++f)
#pragma unroll
    for (int m = 0; m < 2; ++m)
#pragma unroll
      for (int j = 0; j < 4; ++j) {
        const float kkv = elu1(acc[m][f][j]);
        pkv[f] += kkv * acc[m][f + 4][j];
        pden[f] += kkv;
      }
#pragma unroll
  for (int f = 0; f < 4; ++f) {
    pkv[f] += __shfl_xor(pkv[f], 16, 64);
    pkv[f] += __shfl_xor(pkv[f], 32, 64);
    pden[f] += __shfl_xor(pden[f], 16, 64);
    pden[f] += __shfl_xor(pden[f], 32, 64);
  }
  if (lane < 16) {
#pragma unroll
    for (int f = 0; f < 4; ++f) {
      const int c = cc0 + f * 16 + lane;
      atomicAdd(&kv[b * NC + c], pkv[f]);
      atomicAdd(&den[b * NC + c], pden[f]);
    }
  }
}

__global__ __launch_bounds__(256) void k_ws(const float* __restrict__ wout,
                                            const float* __restrict__ kv,
                                            const float* __restrict__ den,
                                            f16* __restrict__ wsc) {
  int i = blockIdx.x * 256 + threadIdx.x;  // 16*256*256
  int c = i & 255;
  int o = (i >> 8) & 255;
  int b = i >> 16;
  float s = kv[b * 256 + c] / fmaxf(den[b * 256 + c], 1e-6f);
  wsc[i] = (f16)(wout[o * 256 + c] * s * 1024.0f);
}

// D[o][n] = sum_c wsc[b][o][c] * qh[b][n][c]; fused LayerNorm over o (256) per column n.
__global__ __launch_bounds__(256) void k_gemm2_ln(const f16* __restrict__ wsc,
                                                  const f16* __restrict__ qh,
                                                  const float* __restrict__ gamma,
                                                  const float* __restrict__ beta,
                                                  float* __restrict__ out) {
  __shared__ __align__(16) f16 At[256 * 64];
  __shared__ __align__(16) f16 Bt[64 * 64];
  __shared__ float red1[4][64];
  __shared__ float red2[4][64];
  __shared__ float smu[64], srs[64];
  const int b = blockIdx.y;
  const int n0 = blockIdx.x * 64;
  const int tid = threadIdx.x;
  const int lane = tid & 63;
  const int wv = tid >> 6;   // wave owns o rows [wv*64, wv*64+64)
  const int l15 = lane & 15, lg = lane >> 4;
  const int srow = lane >> 3;
  const int sch = (lane & 7) * 8;
  const f16* wsb = wsc + (size_t)b * NC * NC;

  f32x4 acc[4][4] = {};

  for (int ks = 0; ks < 4; ++ks) {
    const int c0 = ks * 64;
#pragma unroll
    for (int it = 0; it < 8; ++it) {
      const int seg = wv * 8 + it;       // 0..31
      const int row = seg * 8 + srow;    // 0..255
      gload16(wsb + (size_t)row * NC + c0 + sch, At + seg * 512);
    }
#pragma unroll
    for (int it = 0; it < 2; ++it) {
      const int seg = wv * 2 + it;       // 0..7
      const int row = seg * 8 + srow;    // 0..63
      gload16(qh + ((size_t)(b * NN + n0 + row)) * NC + c0 + sch, Bt + seg * 512);
    }
    __syncthreads();
#pragma unroll
    for (int kk = 0; kk < 2; ++kk) {
      const int kb = kk * 32 + lg * 8;
      f16x8 af[4], bf[4];
#pragma unroll
      for (int m = 0; m < 4; ++m)
        af[m] = *(const f16x8*)(At + (wv * 64 + m * 16 + l15) * 64 + kb);
#pragma unroll
      for (int f = 0; f < 4; ++f)
        bf[f] = *(const f16x8*)(Bt + (f * 16 + l15) * 64 + kb);
#pragma unroll
      for (int m = 0; m < 4; ++m)
#pragma unroll
        for (int f = 0; f < 4; ++f)
          acc[m][f] = __builtin_amdgcn_mfma_f32_16x16x32_f16(af[m], bf[f], acc[m][f], 0, 0, 0);
    }
    __syncthreads();
  }
  float s1[4] = {0, 0, 0, 0}, s2[4] = {0, 0, 0, 0};
#pragma unroll
  for (int f = 0; f < 4; ++f)
#pragma unroll
    for (int m = 0; m < 4; ++m)
#pragma unroll
      for (int j = 0; j < 4; ++j) {
        const float v = acc[m][f][j];
        s1[f] += v;
        s2[f] += v * v;
      }
#pragma unroll
  for (int f = 0; f < 4; ++f) {
    s1[f] += __shfl_xor(s1[f], 16, 64);
    s1[f] += __shfl_xor(s1[f], 32, 64);
    s2[f] += __shfl_xor(s2[f], 16, 64);
    s2[f] += __shfl_xor(s2[f], 32, 64);
  }
  if (lane < 16) {
#pragma unroll
    for (int f = 0; f < 4; ++f) {
      red1[wv][f * 16 + lane] = s1[f];
      red2[wv][f * 16 + lane] = s2[f];
    }
  }
  __syncthreads();
  if (tid < 64) {
    const float a1 = red1[0][tid] + red1[1][tid] + red1[2][tid] + red1[3][tid];
    const float a2 = red2[0][tid] + red2[1][tid] + red2[2][tid] + red2[3][tid];
    const float mu = a1 * (IOSCALE / 256.f);
    const float e2 = a2 * (IOSCALE * IOSCALE / 256.f);
    smu[tid] = mu;
    srs[tid] = rsqrtf(e2 - mu * mu + LN_EPS);
  }
  __syncthreads();
#pragma unroll
  for (int m = 0; m < 4; ++m) {
    const int ob = wv * 64 + m * 16 + lg * 4;
#pragma unroll
    for (int j = 0; j < 4; ++j) {
      const int o = ob + j;
      const float g = gamma[o], be = beta[o];
#pragma unroll
      for (int f = 0; f < 4; ++f) {
        const int col = f * 16 + l15;
        const float v = acc[m][f][j] * IOSCALE;
        out[((size_t)(b * NC + o)) * NN + n0 + col] = (v - smu[col]) * srs[col] * g + be;
      }
    }
  }
}

extern "C" void kernel_launch(void* const* d_in, const int* in_sizes, int n_in,
                              void* d_out, int out_size, void* d_ws, size_t ws_size,
                              hipStream_t stream) {
  const float* x = (const float*)d_in[0];
  const float* w_qkv = (const float*)d_in[1];
  const float* w_out = (const float*)d_in[2];
  const float* ln_g = (const float*)d_in[3];
  const float* ln_b = (const float*)d_in[4];
  float* out = (float*)d_out;

  char* wsb = (char*)d_ws;
  const size_t OFF_WH = 0;                       // 768*256*2   = 393216
  const size_t OFF_XH = OFF_WH + 393216;         // 16*4096*256*2 = 32 MiB
  const size_t OFF_QH = OFF_XH + 33554432;       // 32 MiB
  const size_t OFF_KV = OFF_QH + 33554432;       // 16 KiB
  const size_t OFF_DEN = OFF_KV + 16384;         // 16 KiB
  const size_t OFF_WSC = OFF_DEN + 16384;        // 2 MiB

  f16* wh = (f16*)(wsb + OFF_WH);
  f16* xh = (f16*)(wsb + OFF_XH);
  f16* qh = (f16*)(wsb + OFF_QH);
  float* kv = (float*)(wsb + OFF_KV);
  float* den = (float*)(wsb + OFF_DEN);
  f16* wsc = (f16*)(wsb + OFF_WSC);

  hipMemsetAsync(kv, 0, 2 * 16384, stream);

  k_convw<<<768, 256, 0, stream>>>(w_qkv, wh, 768 * 256);
  k_transpose<<<dim3(64, 4, 16), 256, 0, stream>>>(x, xh);
  k_gemm_q<<<dim3(32, 2, 16), 256, 0, stream>>>(xh, wh, qh);
  k_gemm_kv<<<dim3(32, 4, 16), 256, 0, stream>>>(xh, wh, kv, den);
  k_ws<<<4096, 256, 0, stream>>>(w_out, kv, den, wsc);
  k_gemm2_ln<<<dim3(64, 16), 256, 0, stream>>>(wsc, qh, ln_g, ln_b, out);
}